// Round 3
// baseline (627.170 us; speedup 1.0000x reference)
//
#include <hip/hip_runtime.h>
#include <hip/hip_bf16.h>

typedef unsigned short u16;
typedef unsigned char  u8;
typedef unsigned int   u32;
typedef __attribute__((ext_vector_type(8))) short  short8;
typedef __attribute__((ext_vector_type(8))) __bf16 bf16x8;
typedef __attribute__((ext_vector_type(4))) float  f32x4;
typedef __attribute__((ext_vector_type(4))) int    i32x4;

#define DI static __device__ __forceinline__

constexpr int T_ = 4, B_ = 64, C_ = 384, N_ = 196, NH_ = 8, DH_ = 48;
constexpr int J1_ = B_ * N_;           // 12544 columns per t-slice (= 98*128 = 49*256)
constexpr int K2_ = 2 * C_;            // 768 (hi|lo split-K)
constexpr int M1_ = 3 * C_;            // 1152 (q|k|v output channels)
constexpr int NSP_ = 208;              // padded n-stride for spike tensors

DI u16 f2bf(float x){ __hip_bfloat16 h = __float2bfloat16(x); u16 u; __builtin_memcpy(&u,&h,2); return u; }
DI float bf2f(u16 u){ __hip_bfloat16 h; __builtin_memcpy(&h,&u,2); return __bfloat162float(h); }

DI void gload16(const void* g, void* lds){
  __builtin_amdgcn_global_load_lds((const __attribute__((address_space(1))) u32*)g,
                                   (__attribute__((address_space(3))) u32*)lds, 16, 0, 0);
}
DI bf16x8 ldbf8(const u16* p){ short8 v = *(const short8*)p; return __builtin_bit_cast(bf16x8, v); }

// ---------------------------------------------------------------- K0: prep
__global__ __launch_bounds__(256) void k0_prep(
    const float* __restrict__ qw, const float* __restrict__ kw,
    const float* __restrict__ vw, const float* __restrict__ pw,
    const float* __restrict__ qbn, const float* __restrict__ kbn,
    const float* __restrict__ vbn, const float* __restrict__ pbn,
    u16* __restrict__ A2, u16* __restrict__ A2p,
    float* __restrict__ invq, float* __restrict__ betaq,
    float* __restrict__ invp, float* __restrict__ betap)
{
  int id = blockIdx.x * 256 + threadIdx.x;
  const int nA = M1_ * K2_, nP = C_ * K2_;
  if (id < nA) {
    int cc = id / K2_, k = id % K2_;
    int br = cc / C_, row = cc % C_;
    const float* w = (br == 0) ? qw : ((br == 1) ? kw : vw);
    float wv = w[row * C_ + (k < C_ ? k : k - C_)];
    u16 hi = f2bf(wv);
    A2[id] = (k < C_) ? hi : f2bf(__fsub_rn(wv, bf2f(hi)));
  } else if (id < nA + nP) {
    int id2 = id - nA;
    int cc = id2 / K2_, k = id2 % K2_;
    float wv = pw[cc * C_ + (k < C_ ? k : k - C_)];
    u16 hi = f2bf(wv);
    A2p[id2] = (k < C_) ? hi : f2bf(__fsub_rn(wv, bf2f(hi)));
  } else if (id < nA + nP + M1_) {
    int c = id - nA - nP;
    int br = c / C_, cr = c % C_;
    const float* p = (br == 0) ? qbn : ((br == 1) ? kbn : vbn);
    float g = p[cr], bb = p[C_ + cr], mm = p[2*C_ + cr], vv = p[3*C_ + cr];
    float inv = g / sqrtf(__fadd_rn(vv, 1e-5f));
    invq[c] = inv; betaq[c] = __fsub_rn(bb, __fmul_rn(mm, inv));
  } else if (id < nA + nP + M1_ + C_) {
    int c = id - nA - nP - M1_;
    float g = pbn[c], bb = pbn[C_ + c], mm = pbn[2*C_ + c], vv = pbn[3*C_ + c];
    float inv = g / sqrtf(__fadd_rn(vv, 1e-5f));
    invp[c] = inv; betap[c] = __fsub_rn(bb, __fmul_rn(mm, inv));
  }
}

// ---------------------------------------------------------------- K1: LIF(x) -> xs_t[j][c]
__global__ __launch_bounds__(256) void k1_lif_x(const float* __restrict__ x, u16* __restrict__ xs_t)
{
  int b = blockIdx.x / 12, ch = blockIdx.x % 12;
  int c0 = ch * 32;
  __shared__ u16 sp[4 * 32 * 198];
  int tid = threadIdx.x;
  for (int idx = tid; idx < 32 * N_; idx += 256) {
    int ci = idx / N_, n = idx % N_;
    float v = 0.f;
    for (int t = 0; t < 4; t++) {
      float xv = x[((size_t)((t*B_ + b)*C_ + c0 + ci))*N_ + n];
      v = __fadd_rn(v, __fmul_rn(__fsub_rn(xv, v), 0.5f));
      bool s = (v >= 1.0f);
      sp[(t*32 + ci)*198 + n] = s ? (u16)0x3F80 : (u16)0;
      v = __fmul_rn(v, s ? 0.f : 1.f);
    }
  }
  __syncthreads();
  for (int idx = tid; idx < 4 * 32 * N_; idx += 256) {
    int ci = idx & 31; int q = idx >> 5; int n = q % N_; int t = q / N_;
    xs_t[((size_t)((t*B_ + b)*N_ + n))*C_ + c0 + ci] = sp[(t*32 + ci)*198 + n];
  }
}

// ---------------------------------------------------------------- G1: branch GEMM (m97 structure + swizzle, flat-j tiles)
// grid: 9 bm x 98 jt; each block owns the same 128-column subset in all 4 t-slices.
__global__ __launch_bounds__(256, 2) void g1_branch(
    const u16* __restrict__ A2, const u16* __restrict__ xs_t,
    const float* __restrict__ invq, const float* __restrict__ betaq,
    u8* __restrict__ qs, u8* __restrict__ ks_, u8* __restrict__ vs)
{
  int blk = blockIdx.x;
  int bm = blk % 9, jt = blk / 9;
  int cc0 = bm * 128;
  int colb = jt * 128;

  __shared__ u16 At[128 * 64];
  __shared__ u16 Bt[128 * 64];

  int tid = threadIdx.x;
  int lane = tid & 63, w = tid >> 6;
  int lr = lane & 15, lg = lane >> 4;
  int rsw = lr & 7;
  int mrow = (w & 1) * 64, ncol = (w >> 1) * 64;
  int Lb = w * 256;

  float vst[4][4][4];
  #pragma unroll
  for (int a = 0; a < 4; a++)
    #pragma unroll
    for (int bq = 0; bq < 4; bq++)
      #pragma unroll
      for (int r = 0; r < 4; r++) vst[a][bq][r] = 0.f;

  for (int t = 0; t < 4; t++) {
    f32x4 acc[4][4];
    #pragma unroll
    for (int a = 0; a < 4; a++)
      #pragma unroll
      for (int bq = 0; bq < 4; bq++) acc[a][bq] = (f32x4){0.f, 0.f, 0.f, 0.f};

    long j0 = (long)t * J1_ + colb;

    for (int kt = 0; kt < 12; kt++) {
      int ckA = kt * 64;
      int ckB = (ckA >= C_) ? (ckA - C_) : ckA;
      #pragma unroll
      for (int i = 0; i < 4; i++) {
        int L0 = Lb + i * 64;
        int L = L0 + lane;
        int r = L >> 3;
        int c = (L & 7) ^ (r & 7);          // inverse-swizzled source chunk
        gload16(A2 + (size_t)(cc0 + r) * K2_ + ckA + c * 8, &At[L0 * 8]);
        gload16(xs_t + (size_t)(j0 + r) * C_ + ckB + c * 8, &Bt[L0 * 8]);
      }
      __syncthreads();
      #pragma unroll
      for (int ks2 = 0; ks2 < 2; ks2++) {
        bf16x8 af[4], bfr[4];
        #pragma unroll
        for (int mt = 0; mt < 4; mt++)
          af[mt]  = ldbf8(&At[(mrow + mt*16 + lr)*64 + (((ks2*4 + lg) ^ rsw) * 8)]);
        #pragma unroll
        for (int nn = 0; nn < 4; nn++)
          bfr[nn] = ldbf8(&Bt[(ncol + nn*16 + lr)*64 + (((ks2*4 + lg) ^ rsw) * 8)]);
        #pragma unroll
        for (int mt = 0; mt < 4; mt++)
          #pragma unroll
          for (int nn = 0; nn < 4; nn++)
            acc[mt][nn] = __builtin_amdgcn_mfma_f32_16x16x32_bf16(af[mt], bfr[nn], acc[mt][nn], 0, 0, 0);
      }
      __syncthreads();
    }

    #pragma unroll
    for (int mt = 0; mt < 4; mt++) {
      #pragma unroll
      for (int r = 0; r < 4; r++) {
        int cc = cc0 + mrow + mt*16 + lg*4 + r;
        float inv = invq[cc], beta = betaq[cc];
        int br = cc / C_, c = cc % C_;
        int h = c / DH_, dd = c % DH_;
        u8* dstb = (br == 0) ? qs : ((br == 1) ? ks_ : vs);
        #pragma unroll
        for (int nn = 0; nn < 4; nn++) {
          int col = colb + ncol + nn*16 + lr;
          u32 bb = ((u32)col * 85599u) >> 24;     // exact col/196 for col<12544
          int n = col - (int)bb * 196;
          float yb = __fadd_rn(__fmul_rn(acc[mt][nn][r], inv), beta);
          float v = vst[mt][nn][r];
          v = __fadd_rn(v, __fmul_rn(__fsub_rn(yb, v), 0.5f));
          bool sgl = (v >= 1.0f);
          vst[mt][nn][r] = __fmul_rn(v, sgl ? 0.f : 1.f);
          dstb[(((size_t)(t*B_ + (int)bb)*NH_ + h)*DH_ + dd)*NSP_ + n] = sgl ? (u8)1 : (u8)0;
        }
      }
    }
  }
}

// ---------------------------------------------------------------- K3: attention (exact i8 MFMA) + attn_lif fused over T
__global__ __launch_bounds__(256) void k3_attn(
    const u8* __restrict__ qs, const u8* __restrict__ ks_, const u8* __restrict__ vs,
    u16* __restrict__ s2t)
{
  int b = blockIdx.x >> 3, h = blockIdx.x & 7;
  __shared__ __align__(16) signed char qL[208 * 80];
  __shared__ __align__(16) signed char kL[208 * 80];
  __shared__ __align__(16) signed char vL[48 * 272];
  __shared__ __align__(16) signed char aL[4 * 16 * 272];

  int tid = threadIdx.x, lane = tid & 63, w = tid >> 6;
  int lr = lane & 15, lg = lane >> 4;

  for (int i = tid; i < 208*80/4; i += 256) { ((int*)qL)[i] = 0; ((int*)kL)[i] = 0; }
  for (int i = tid; i < 48*272/4; i += 256) ((int*)vL)[i] = 0;
  for (int i = tid; i < 4*16*272/4; i += 256) ((int*)aL)[i] = 0;
  __syncthreads();

  float vst[4][3][4];
  #pragma unroll
  for (int a = 0; a < 4; a++)
    #pragma unroll
    for (int d = 0; d < 3; d++)
      #pragma unroll
      for (int r = 0; r < 4; r++) vst[a][d][r] = 0.f;

  signed char* arow = &aL[w * 16 * 272];
  const i32x4 zero4 = {0, 0, 0, 0};

  for (int t = 0; t < 4; t++) {
    size_t base = ((size_t)((t*B_ + b)*NH_ + h)) * (DH_ * NSP_);
    // stage exactly 196 valid bytes per row (49 u32); pads stay zero from init
    for (int i = tid; i < 48 * 49; i += 256) {
      int dd = i / 49, n4 = i % 49;
      u32 qv = *(const u32*)(qs + base + dd*NSP_ + n4*4);
      u32 kv = *(const u32*)(ks_ + base + dd*NSP_ + n4*4);
      u32 vv = *(const u32*)(vs + base + dd*NSP_ + n4*4);
      #pragma unroll
      for (int jj = 0; jj < 4; jj++) {
        qL[(n4*4 + jj)*80 + dd] = (signed char)((qv >> (8*jj)) & 0xFF);
        kL[(n4*4 + jj)*80 + dd] = (signed char)((kv >> (8*jj)) & 0xFF);
      }
      *(u32*)(vL + dd*272 + n4*4) = vv;
    }
    __syncthreads();

    int nslots = (w == 0) ? 4 : 3;
    for (int sl = 0; sl < nslots; sl++) {
      int ni = w + sl * 4;
      i32x4 afr = *reinterpret_cast<const i32x4*>(qL + (ni*16 + lr)*80 + lg*16);
      for (int mj = 0; mj < 13; mj++) {
        i32x4 bfr = *reinterpret_cast<const i32x4*>(kL + (mj*16 + lr)*80 + lg*16);
        i32x4 d = __builtin_amdgcn_mfma_i32_16x16x64_i8(afr, bfr, zero4, 0, 0, 0);
        #pragma unroll
        for (int r = 0; r < 4; r++)
          arow[(lg*4 + r)*272 + mj*16 + lr] = (signed char)d[r];
      }
      #pragma unroll
      for (int di = 0; di < 3; di++) {
        i32x4 acc = zero4;
        #pragma unroll
        for (int ks2 = 0; ks2 < 4; ks2++) {
          i32x4 aa = *reinterpret_cast<const i32x4*>(arow + lr*272 + ks2*64 + lg*16);
          i32x4 bb = *reinterpret_cast<const i32x4*>(vL + (di*16 + lr)*272 + ks2*64 + lg*16);
          acc = __builtin_amdgcn_mfma_i32_16x16x64_i8(aa, bb, acc, 0, 0, 0);
        }
        #pragma unroll
        for (int r = 0; r < 4; r++) {
          int n = ni*16 + lg*4 + r;
          float xv = __fmul_rn((float)acc[r], 0.125f);
          float v = vst[sl][di][r];
          v = __fadd_rn(v, __fmul_rn(__fsub_rn(xv, v), 0.5f));
          bool s = (v >= 0.5f);
          vst[sl][di][r] = __fmul_rn(v, s ? 0.f : 1.f);
          if (n < N_)
            s2t[((size_t)((t*B_ + b)*N_ + n))*C_ + h*DH_ + di*16 + lr] = s ? (u16)0x3F80 : (u16)0;
        }
      }
    }
    __syncthreads();
  }
}

// ---------------------------------------------------------------- G2: proj GEMM (m97 structure + swizzle)
__global__ __launch_bounds__(256, 2) void g2_proj(
    const u16* __restrict__ A2p, const u16* __restrict__ s2t,
    const float* __restrict__ invp, const float* __restrict__ betap,
    const float* __restrict__ pb, const float* __restrict__ x,
    float* __restrict__ out)
{
  int blk = blockIdx.x;
  int bm = blk % 3, bn = blk / 3;
  int cc0 = bm * 128, j0 = bn * 128;

  __shared__ u16 At[128 * 64];
  __shared__ u16 Bt[128 * 64];

  int tid = threadIdx.x;
  int lane = tid & 63, w = tid >> 6;
  int lr = lane & 15, lg = lane >> 4;
  int rsw = lr & 7;
  int mrow = (w & 1) * 64, ncol = (w >> 1) * 64;
  int Lb = w * 256;

  f32x4 acc[4][4];
  #pragma unroll
  for (int a = 0; a < 4; a++)
    #pragma unroll
    for (int bq = 0; bq < 4; bq++) acc[a][bq] = (f32x4){0.f, 0.f, 0.f, 0.f};

  for (int kt = 0; kt < 12; kt++) {
    int ckA = kt * 64;
    int ckB = (ckA >= C_) ? (ckA - C_) : ckA;
    #pragma unroll
    for (int i = 0; i < 4; i++) {
      int L0 = Lb + i * 64;
      int L = L0 + lane;
      int r = L >> 3;
      int c = (L & 7) ^ (r & 7);
      gload16(A2p + (size_t)(cc0 + r) * K2_ + ckA + c * 8, &At[L0 * 8]);
      gload16(s2t + (size_t)(j0 + r) * C_ + ckB + c * 8, &Bt[L0 * 8]);
    }
    __syncthreads();
    #pragma unroll
    for (int ks2 = 0; ks2 < 2; ks2++) {
      bf16x8 af[4], bfr[4];
      #pragma unroll
      for (int mt = 0; mt < 4; mt++)
        af[mt]  = ldbf8(&At[(mrow + mt*16 + lr)*64 + (((ks2*4 + lg) ^ rsw) * 8)]);
      #pragma unroll
      for (int nn = 0; nn < 4; nn++)
        bfr[nn] = ldbf8(&Bt[(ncol + nn*16 + lr)*64 + (((ks2*4 + lg) ^ rsw) * 8)]);
      #pragma unroll
      for (int mt = 0; mt < 4; mt++)
        #pragma unroll
        for (int nn = 0; nn < 4; nn++)
          acc[mt][nn] = __builtin_amdgcn_mfma_f32_16x16x32_bf16(af[mt], bfr[nn], acc[mt][nn], 0, 0, 0);
    }
    __syncthreads();
  }

  #pragma unroll
  for (int mt = 0; mt < 4; mt++) {
    #pragma unroll
    for (int r = 0; r < 4; r++) {
      int cc = cc0 + mrow + mt*16 + lg*4 + r;
      float inv = invp[cc], beta = betap[cc], pbv = pb[cc];
      #pragma unroll
      for (int nn = 0; nn < 4; nn++) {
        int j = j0 + ncol + nn*16 + lr;
        float y = __fadd_rn(acc[mt][nn][r], pbv);
        float o = __fadd_rn(__fmul_rn(y, inv), beta);
        int jq = j / N_, n = j % N_;
        size_t addr = ((size_t)jq * C_ + cc) * N_ + n;
        out[addr] = __fadd_rn(o, x[addr]);
      }
    }
  }
}

// ---------------------------------------------------------------- launch
extern "C" void kernel_launch(void* const* d_in, const int* in_sizes, int n_in,
                              void* d_out, int out_size, void* d_ws, size_t ws_size,
                              hipStream_t stream)
{
  (void)in_sizes; (void)n_in; (void)out_size; (void)ws_size;
  const float* x   = (const float*)d_in[0];
  const float* qw  = (const float*)d_in[1];
  const float* kw  = (const float*)d_in[2];
  const float* vw  = (const float*)d_in[3];
  const float* pw  = (const float*)d_in[4];
  const float* pbv = (const float*)d_in[5];
  const float* qbn = (const float*)d_in[6];
  const float* kbn = (const float*)d_in[7];
  const float* vbn = (const float*)d_in[8];
  const float* pbn = (const float*)d_in[9];

  char* ws = (char*)d_ws;
  u16*   A2    = (u16*)  (ws + 0);         // 1152*768*2   = 1769472
  u16*   A2p   = (u16*)  (ws + 1769472);   // 384*768*2    = 589824
  float* invq  = (float*)(ws + 2359296);
  float* betaq = (float*)(ws + 2363904);
  float* invp  = (float*)(ws + 2368512);
  float* betap = (float*)(ws + 2370048);
  u16*   xs_t  = (u16*)  (ws + 2371584);   // 50240*384*2  = 38584320
  u16*   s2t   = xs_t;                     // aliased: consumed by G1 before K3 writes
  u8*    qs    = (u8*)   (ws + 40955904);  // 256*8*48*208 = 20447232
  u8*    ks    = (u8*)   (ws + 61403136);
  u8*    vs    = (u8*)   (ws + 81850368);  // end = 102297600 bytes

  k0_prep<<<4614, 256, 0, stream>>>(qw, kw, vw, pw, qbn, kbn, vbn, pbn,
                                    A2, A2p, invq, betaq, invp, betap);
  k1_lif_x<<<768, 256, 0, stream>>>(x, xs_t);
  g1_branch<<<882, 256, 0, stream>>>(A2, xs_t, invq, betaq, qs, ks, vs);
  k3_attn<<<512, 256, 0, stream>>>(qs, ks, vs, s2t);
  g2_proj<<<1176, 256, 0, stream>>>(A2p, s2t, invp, betap, pbv, x, (float*)d_out);
}

// Round 4
// 383.516 us; speedup vs baseline: 1.6353x; 1.6353x over previous
//
#include <hip/hip_runtime.h>
#include <hip/hip_bf16.h>

typedef unsigned short u16;
typedef unsigned char  u8;
typedef unsigned int   u32;
typedef __attribute__((ext_vector_type(8))) short  short8;
typedef __attribute__((ext_vector_type(8))) __bf16 bf16x8;
typedef __attribute__((ext_vector_type(4))) float  f32x4;
typedef __attribute__((ext_vector_type(4))) int    i32x4;

#define DI static __device__ __forceinline__

constexpr int T_ = 4, B_ = 64, C_ = 384, N_ = 196, NH_ = 8, DH_ = 48;
constexpr int J1_ = B_ * N_;           // 12544 columns per t-slice (= 98*128)
constexpr int J_  = T_ * J1_;          // 50176 flat columns
constexpr int K2_ = 2 * C_;            // 768 (hi|lo split-K)
constexpr int M1_ = 3 * C_;            // 1152 (q|k|v output channels)

DI u16 f2bf(float x){ __hip_bfloat16 h = __float2bfloat16(x); u16 u; __builtin_memcpy(&u,&h,2); return u; }
DI float bf2f(u16 u){ __hip_bfloat16 h; __builtin_memcpy(&h,&u,2); return __bfloat162float(h); }

DI void gload16(const void* g, void* lds){
  __builtin_amdgcn_global_load_lds((const __attribute__((address_space(1))) u32*)g,
                                   (__attribute__((address_space(3))) u32*)lds, 16, 0, 0);
}
DI bf16x8 ldbf8(const u16* p){ short8 v = *(const short8*)p; return __builtin_bit_cast(bf16x8, v); }

// ---------------------------------------------------------------- K0: prep
__global__ __launch_bounds__(256) void k0_prep(
    const float* __restrict__ qw, const float* __restrict__ kw,
    const float* __restrict__ vw, const float* __restrict__ pw,
    const float* __restrict__ qbn, const float* __restrict__ kbn,
    const float* __restrict__ vbn, const float* __restrict__ pbn,
    u16* __restrict__ A2, u16* __restrict__ A2p,
    float* __restrict__ invq, float* __restrict__ betaq,
    float* __restrict__ invp, float* __restrict__ betap)
{
  int id = blockIdx.x * 256 + threadIdx.x;
  const int nA = M1_ * K2_, nP = C_ * K2_;
  if (id < nA) {
    int cc = id / K2_, k = id % K2_;
    int br = cc / C_, row = cc % C_;
    const float* w = (br == 0) ? qw : ((br == 1) ? kw : vw);
    float wv = w[row * C_ + (k < C_ ? k : k - C_)];
    u16 hi = f2bf(wv);
    A2[id] = (k < C_) ? hi : f2bf(__fsub_rn(wv, bf2f(hi)));
  } else if (id < nA + nP) {
    int id2 = id - nA;
    int cc = id2 / K2_, k = id2 % K2_;
    float wv = pw[cc * C_ + (k < C_ ? k : k - C_)];
    u16 hi = f2bf(wv);
    A2p[id2] = (k < C_) ? hi : f2bf(__fsub_rn(wv, bf2f(hi)));
  } else if (id < nA + nP + M1_) {
    int c = id - nA - nP;
    int br = c / C_, cr = c % C_;
    const float* p = (br == 0) ? qbn : ((br == 1) ? kbn : vbn);
    float g = p[cr], bb = p[C_ + cr], mm = p[2*C_ + cr], vv = p[3*C_ + cr];
    float inv = g / sqrtf(__fadd_rn(vv, 1e-5f));
    invq[c] = inv; betaq[c] = __fsub_rn(bb, __fmul_rn(mm, inv));
  } else if (id < nA + nP + M1_ + C_) {
    int c = id - nA - nP - M1_;
    float g = pbn[c], bb = pbn[C_ + c], mm = pbn[2*C_ + c], vv = pbn[3*C_ + c];
    float inv = g / sqrtf(__fadd_rn(vv, 1e-5f));
    invp[c] = inv; betap[c] = __fsub_rn(bb, __fmul_rn(mm, inv));
  }
}

// ---------------------------------------------------------------- K1: LIF(x) -> xs_t[j][c]
__global__ __launch_bounds__(256) void k1_lif_x(const float* __restrict__ x, u16* __restrict__ xs_t)
{
  int b = blockIdx.x / 12, ch = blockIdx.x % 12;
  int c0 = ch * 32;
  __shared__ u16 sp[4 * 32 * 198];
  int tid = threadIdx.x;
  for (int idx = tid; idx < 32 * N_; idx += 256) {
    int ci = idx / N_, n = idx % N_;
    float v = 0.f;
    for (int t = 0; t < 4; t++) {
      float xv = x[((size_t)((t*B_ + b)*C_ + c0 + ci))*N_ + n];
      v = __fadd_rn(v, __fmul_rn(__fsub_rn(xv, v), 0.5f));
      bool s = (v >= 1.0f);
      sp[(t*32 + ci)*198 + n] = s ? (u16)0x3F80 : (u16)0;
      v = __fmul_rn(v, s ? 0.f : 1.f);
    }
  }
  __syncthreads();
  for (int idx = tid; idx < 4 * 32 * N_; idx += 256) {
    int ci = idx & 31; int q = idx >> 5; int n = q % N_; int t = q / N_;
    xs_t[((size_t)((t*B_ + b)*N_ + n))*C_ + c0 + ci] = sp[(t*32 + ci)*198 + n];
  }
}

// ---------------------------------------------------------------- G1: branch GEMM (m97 + swizzle, flat-j, XCD-local B)
// grid 9*104: bm = blk/104 (A-tile), jt = blk%104 (<98). Same-jt blocks 104 apart => same XCD.
// Spike layout: qs/ks/vs[c][J_] with j = t*J1_ + col; epilogue writes 64B-aligned contiguous.
__global__ __launch_bounds__(256, 2) void g1_branch(
    const u16* __restrict__ A2, const u16* __restrict__ xs_t,
    const float* __restrict__ invq, const float* __restrict__ betaq,
    u8* __restrict__ qs, u8* __restrict__ ks_, u8* __restrict__ vs)
{
  int bm = blockIdx.x / 104, jt = blockIdx.x % 104;
  if (jt >= 98) return;
  int cc0 = bm * 128;
  int colb = jt * 128;

  __shared__ u16 At[128 * 64];
  __shared__ u16 Bt[128 * 64];

  int tid = threadIdx.x;
  int lane = tid & 63, w = tid >> 6;
  int lr = lane & 15, lg = lane >> 4;
  int rsw = lr & 7;
  int mrow = (w & 1) * 64, ncol = (w >> 1) * 64;
  int Lb = w * 256;

  float vst[4][4][4];
  #pragma unroll
  for (int a = 0; a < 4; a++)
    #pragma unroll
    for (int bq = 0; bq < 4; bq++)
      #pragma unroll
      for (int r = 0; r < 4; r++) vst[a][bq][r] = 0.f;

  for (int t = 0; t < 4; t++) {
    f32x4 acc[4][4];
    #pragma unroll
    for (int a = 0; a < 4; a++)
      #pragma unroll
      for (int bq = 0; bq < 4; bq++) acc[a][bq] = (f32x4){0.f, 0.f, 0.f, 0.f};

    long j0 = (long)t * J1_ + colb;

    for (int kt = 0; kt < 12; kt++) {
      int ckA = kt * 64;
      int ckB = (ckA >= C_) ? (ckA - C_) : ckA;
      #pragma unroll
      for (int i = 0; i < 4; i++) {
        int L0 = Lb + i * 64;
        int L = L0 + lane;
        int r = L >> 3;
        int c = (L & 7) ^ (r & 7);          // inverse-swizzled source chunk
        gload16(A2 + (size_t)(cc0 + r) * K2_ + ckA + c * 8, &At[L0 * 8]);
        gload16(xs_t + (size_t)(j0 + r) * C_ + ckB + c * 8, &Bt[L0 * 8]);
      }
      __syncthreads();
      #pragma unroll
      for (int ks2 = 0; ks2 < 2; ks2++) {
        bf16x8 af[4], bfr[4];
        #pragma unroll
        for (int mt = 0; mt < 4; mt++)
          af[mt]  = ldbf8(&At[(mrow + mt*16 + lr)*64 + (((ks2*4 + lg) ^ rsw) * 8)]);
        #pragma unroll
        for (int nn = 0; nn < 4; nn++)
          bfr[nn] = ldbf8(&Bt[(ncol + nn*16 + lr)*64 + (((ks2*4 + lg) ^ rsw) * 8)]);
        #pragma unroll
        for (int mt = 0; mt < 4; mt++)
          #pragma unroll
          for (int nn = 0; nn < 4; nn++)
            acc[mt][nn] = __builtin_amdgcn_mfma_f32_16x16x32_bf16(af[mt], bfr[nn], acc[mt][nn], 0, 0, 0);
      }
      __syncthreads();
    }

    #pragma unroll
    for (int mt = 0; mt < 4; mt++) {
      #pragma unroll
      for (int r = 0; r < 4; r++) {
        int cc = cc0 + mrow + mt*16 + lg*4 + r;
        float inv = invq[cc], beta = betaq[cc];
        int br = cc / C_, c = cc % C_;
        u8* dst = ((br == 0) ? qs : ((br == 1) ? ks_ : vs)) + (size_t)c * J_ + t * J1_ + colb;
        #pragma unroll
        for (int nn = 0; nn < 4; nn++) {
          int col = ncol + nn*16 + lr;
          float yb = __fadd_rn(__fmul_rn(acc[mt][nn][r], inv), beta);
          float v = vst[mt][nn][r];
          v = __fadd_rn(v, __fmul_rn(__fsub_rn(yb, v), 0.5f));
          bool sgl = (v >= 1.0f);
          vst[mt][nn][r] = __fmul_rn(v, sgl ? 0.f : 1.f);
          dst[col] = sgl ? (u8)1 : (u8)0;
        }
      }
    }
  }
}

// ---------------------------------------------------------------- K3: attention (exact i8 MFMA) + attn_lif fused over T
__global__ __launch_bounds__(256) void k3_attn(
    const u8* __restrict__ qs, const u8* __restrict__ ks_, const u8* __restrict__ vs,
    u16* __restrict__ s2t)
{
  int b = blockIdx.x >> 3, h = blockIdx.x & 7;
  __shared__ __align__(16) signed char qL[208 * 80];
  __shared__ __align__(16) signed char kL[208 * 80];
  __shared__ __align__(16) signed char vL[48 * 272];
  __shared__ __align__(16) signed char aL[4 * 16 * 272];

  int tid = threadIdx.x, lane = tid & 63, w = tid >> 6;
  int lr = lane & 15, lg = lane >> 4;

  for (int i = tid; i < 208*80/4; i += 256) { ((int*)qL)[i] = 0; ((int*)kL)[i] = 0; }
  for (int i = tid; i < 48*272/4; i += 256) ((int*)vL)[i] = 0;
  for (int i = tid; i < 4*16*272/4; i += 256) ((int*)aL)[i] = 0;
  __syncthreads();

  float vst[4][3][4];
  #pragma unroll
  for (int a = 0; a < 4; a++)
    #pragma unroll
    for (int d = 0; d < 3; d++)
      #pragma unroll
      for (int r = 0; r < 4; r++) vst[a][d][r] = 0.f;

  signed char* arow = &aL[w * 16 * 272];
  const i32x4 zero4 = {0, 0, 0, 0};

  for (int t = 0; t < 4; t++) {
    size_t off = (size_t)(t*B_ + b) * N_;   // byte offset within a channel row
    // stage exactly 196 bytes per dd row (49 u32); pads stay zero from init
    for (int i = tid; i < 48 * 49; i += 256) {
      int dd = i / 49, n4 = i % 49;
      size_t rb = (size_t)(h*DH_ + dd) * J_ + off;
      u32 qv = *(const u32*)(qs + rb + n4*4);
      u32 kv = *(const u32*)(ks_ + rb + n4*4);
      u32 vv = *(const u32*)(vs + rb + n4*4);
      #pragma unroll
      for (int jj = 0; jj < 4; jj++) {
        qL[(n4*4 + jj)*80 + dd] = (signed char)((qv >> (8*jj)) & 0xFF);
        kL[(n4*4 + jj)*80 + dd] = (signed char)((kv >> (8*jj)) & 0xFF);
      }
      *(u32*)(vL + dd*272 + n4*4) = vv;
    }
    __syncthreads();

    int nslots = (w == 0) ? 4 : 3;
    for (int sl = 0; sl < nslots; sl++) {
      int ni = w + sl * 4;
      i32x4 afr = *reinterpret_cast<const i32x4*>(qL + (ni*16 + lr)*80 + lg*16);
      for (int mj = 0; mj < 13; mj++) {
        i32x4 bfr = *reinterpret_cast<const i32x4*>(kL + (mj*16 + lr)*80 + lg*16);
        i32x4 d = __builtin_amdgcn_mfma_i32_16x16x64_i8(afr, bfr, zero4, 0, 0, 0);
        #pragma unroll
        for (int r = 0; r < 4; r++)
          arow[(lg*4 + r)*272 + mj*16 + lr] = (signed char)d[r];
      }
      #pragma unroll
      for (int di = 0; di < 3; di++) {
        i32x4 acc = zero4;
        #pragma unroll
        for (int ks2 = 0; ks2 < 4; ks2++) {
          i32x4 aa = *reinterpret_cast<const i32x4*>(arow + lr*272 + ks2*64 + lg*16);
          i32x4 bb = *reinterpret_cast<const i32x4*>(vL + (di*16 + lr)*272 + ks2*64 + lg*16);
          acc = __builtin_amdgcn_mfma_i32_16x16x64_i8(aa, bb, acc, 0, 0, 0);
        }
        #pragma unroll
        for (int r = 0; r < 4; r++) {
          int n = ni*16 + lg*4 + r;
          float xv = __fmul_rn((float)acc[r], 0.125f);
          float v = vst[sl][di][r];
          v = __fadd_rn(v, __fmul_rn(__fsub_rn(xv, v), 0.5f));
          bool s = (v >= 0.5f);
          vst[sl][di][r] = __fmul_rn(v, s ? 0.f : 1.f);
          if (n < N_)
            s2t[((size_t)((t*B_ + b)*N_ + n))*C_ + h*DH_ + di*16 + lr] = s ? (u16)0x3F80 : (u16)0;
        }
      }
    }
    __syncthreads();
  }
}

// ---------------------------------------------------------------- G2: proj GEMM (m97 + swizzle; bm slowest => same-jt same XCD)
__global__ __launch_bounds__(256, 2) void g2_proj(
    const u16* __restrict__ A2p, const u16* __restrict__ s2t,
    const float* __restrict__ invp, const float* __restrict__ betap,
    const float* __restrict__ pb, const float* __restrict__ x,
    float* __restrict__ out)
{
  int bm = blockIdx.x / 392, bn = blockIdx.x % 392;
  int cc0 = bm * 128, j0 = bn * 128;

  __shared__ u16 At[128 * 64];
  __shared__ u16 Bt[128 * 64];

  int tid = threadIdx.x;
  int lane = tid & 63, w = tid >> 6;
  int lr = lane & 15, lg = lane >> 4;
  int rsw = lr & 7;
  int mrow = (w & 1) * 64, ncol = (w >> 1) * 64;
  int Lb = w * 256;

  f32x4 acc[4][4];
  #pragma unroll
  for (int a = 0; a < 4; a++)
    #pragma unroll
    for (int bq = 0; bq < 4; bq++) acc[a][bq] = (f32x4){0.f, 0.f, 0.f, 0.f};

  for (int kt = 0; kt < 12; kt++) {
    int ckA = kt * 64;
    int ckB = (ckA >= C_) ? (ckA - C_) : ckA;
    #pragma unroll
    for (int i = 0; i < 4; i++) {
      int L0 = Lb + i * 64;
      int L = L0 + lane;
      int r = L >> 3;
      int c = (L & 7) ^ (r & 7);
      gload16(A2p + (size_t)(cc0 + r) * K2_ + ckA + c * 8, &At[L0 * 8]);
      gload16(s2t + (size_t)(j0 + r) * C_ + ckB + c * 8, &Bt[L0 * 8]);
    }
    __syncthreads();
    #pragma unroll
    for (int ks2 = 0; ks2 < 2; ks2++) {
      bf16x8 af[4], bfr[4];
      #pragma unroll
      for (int mt = 0; mt < 4; mt++)
        af[mt]  = ldbf8(&At[(mrow + mt*16 + lr)*64 + (((ks2*4 + lg) ^ rsw) * 8)]);
      #pragma unroll
      for (int nn = 0; nn < 4; nn++)
        bfr[nn] = ldbf8(&Bt[(ncol + nn*16 + lr)*64 + (((ks2*4 + lg) ^ rsw) * 8)]);
      #pragma unroll
      for (int mt = 0; mt < 4; mt++)
        #pragma unroll
        for (int nn = 0; nn < 4; nn++)
          acc[mt][nn] = __builtin_amdgcn_mfma_f32_16x16x32_bf16(af[mt], bfr[nn], acc[mt][nn], 0, 0, 0);
    }
    __syncthreads();
  }

  #pragma unroll
  for (int mt = 0; mt < 4; mt++) {
    #pragma unroll
    for (int r = 0; r < 4; r++) {
      int cc = cc0 + mrow + mt*16 + lg*4 + r;
      float inv = invp[cc], beta = betap[cc], pbv = pb[cc];
      #pragma unroll
      for (int nn = 0; nn < 4; nn++) {
        int j = j0 + ncol + nn*16 + lr;
        float y = __fadd_rn(acc[mt][nn][r], pbv);
        float o = __fadd_rn(__fmul_rn(y, inv), beta);
        int jq = j / N_, n = j % N_;
        size_t addr = ((size_t)jq * C_ + cc) * N_ + n;
        out[addr] = __fadd_rn(o, x[addr]);
      }
    }
  }
}

// ---------------------------------------------------------------- launch
extern "C" void kernel_launch(void* const* d_in, const int* in_sizes, int n_in,
                              void* d_out, int out_size, void* d_ws, size_t ws_size,
                              hipStream_t stream)
{
  (void)in_sizes; (void)n_in; (void)out_size; (void)ws_size;
  const float* x   = (const float*)d_in[0];
  const float* qw  = (const float*)d_in[1];
  const float* kw  = (const float*)d_in[2];
  const float* vw  = (const float*)d_in[3];
  const float* pw  = (const float*)d_in[4];
  const float* pbv = (const float*)d_in[5];
  const float* qbn = (const float*)d_in[6];
  const float* kbn = (const float*)d_in[7];
  const float* vbn = (const float*)d_in[8];
  const float* pbn = (const float*)d_in[9];

  char* ws = (char*)d_ws;
  u16*   A2    = (u16*)  (ws + 0);         // 1152*768*2   = 1769472
  u16*   A2p   = (u16*)  (ws + 1769472);   // 384*768*2    = 589824
  float* invq  = (float*)(ws + 2359296);
  float* betaq = (float*)(ws + 2363904);
  float* invp  = (float*)(ws + 2368512);
  float* betap = (float*)(ws + 2370048);
  u16*   xs_t  = (u16*)  (ws + 2371584);   // 50176*384*2  = 38535168
  u16*   s2t   = xs_t;                     // aliased: consumed by G1 before K3 writes
  u8*    qs    = (u8*)   (ws + 40906752);  // 384*50176    = 19267584
  u8*    ks    = (u8*)   (ws + 60174336);
  u8*    vs    = (u8*)   (ws + 79441920);  // end = 98709504 bytes

  k0_prep<<<4614, 256, 0, stream>>>(qw, kw, vw, pw, qbn, kbn, vbn, pbn,
                                    A2, A2p, invq, betaq, invp, betap);
  k1_lif_x<<<768, 256, 0, stream>>>(x, xs_t);
  g1_branch<<<936, 256, 0, stream>>>(A2, xs_t, invq, betaq, qs, ks, vs);
  k3_attn<<<512, 256, 0, stream>>>(qs, ks, vs, s2t);
  g2_proj<<<1176, 256, 0, stream>>>(A2p, s2t, invp, betap, pbv, x, (float*)d_out);
}